// Round 2
// baseline (1381.364 us; speedup 1.0000x reference)
//
#include <hip/hip_runtime.h>
#include <hip/hip_bf16.h>

// K-means (8 clusters, 10 iters) on 64 batches of 512*512 RGB pixels,
// reproducing jax.random bit-exactly for the centroid init.
//
// PRNG variant implemented:
//   - jax_threefry_partitionable = True (modern JAX default)
//   - split is foldlike: keys[i] = full (y0,y1) of TF(key, (0, i))
//   - 32-bit random_bits = y0 ^ y1 of TF(key, (0, i))   [THIS ROUND's change]
//   - permutation = 2 rounds of stable sort by random u32 keys
//     (num_rounds = ceil(3*ln(2^18)/ln(2^32-1)) = 2)
// Fallback ladder if absmax lands 0.1-0.9: y1-only -> y0-only -> original
// (non-partitionable) split/random_bits layout.
//
// Output written as FLOAT32 (round-1 bf16 was wrong: absmax identical to the
// all-zeros stub because only half the f32 buffer got written).

#define NBATCH 64
#define NPIX   262144   // 512*512 = 2^18
#define NCLUST 8
#define NITER  10
#define NBIN   1024
#define CAP2   1024     // round-2 candidates: E=512, sigma~22.6 -> +22 sigma
#define CAP1   512      // per-bin round-1 candidates: E=256, sigma~16 -> +16 sigma
#define THRESH2 (1u << 23)   // bits2 < 2^23 -> E[count]=512
#define IDXMASK 0x3FFFFull

struct WS {
  unsigned long long list2[NBATCH][CAP2];            // (bits2<<18)|i   0.5 MB
  unsigned long long list1[NBATCH][NCLUST][CAP1];    // (bits1<<18)|i   2.0 MB
  unsigned int subkeys[NBATCH][4];                   // s1k0,s1k1,s2k0,s2k1
  unsigned int hist[NBATCH][NBIN];
  unsigned int cnt2[NBATCH];
  unsigned int cnt1[NBATCH][NCLUST];
  unsigned int binr[NBATCH][NCLUST][2];              // bin, intra-bin rank
  float centroids[NBATCH][NCLUST][3];
  float sums[NBATCH][NCLUST][4];                     // sx,sy,sz,count
};

__device__ __forceinline__ unsigned int rotl32(unsigned int x, int d) {
  return (x << d) | (x >> (32 - d));
}

__device__ __forceinline__ void threefry2x32(unsigned int k0, unsigned int k1,
                                             unsigned int x0, unsigned int x1,
                                             unsigned int &y0, unsigned int &y1) {
  const unsigned int ks2 = k0 ^ k1 ^ 0x1BD11BDAu;
  x0 += k0; x1 += k1;
#define TF_ROUND(r) { x0 += x1; x1 = rotl32(x1, r); x1 ^= x0; }
  TF_ROUND(13) TF_ROUND(15) TF_ROUND(26) TF_ROUND(6)
  x0 += k1;  x1 += ks2 + 1u;
  TF_ROUND(17) TF_ROUND(29) TF_ROUND(16) TF_ROUND(24)
  x0 += ks2; x1 += k0 + 2u;
  TF_ROUND(13) TF_ROUND(15) TF_ROUND(26) TF_ROUND(6)
  x0 += k0;  x1 += k1 + 3u;
  TF_ROUND(17) TF_ROUND(29) TF_ROUND(16) TF_ROUND(24)
  x0 += k1;  x1 += ks2 + 4u;
  TF_ROUND(13) TF_ROUND(15) TF_ROUND(26) TF_ROUND(6)
  x0 += ks2; x1 += k0 + 5u;
#undef TF_ROUND
  y0 = x0; y1 = x1;
}

// 32-bit random_bits, partitionable threefry: XOR of both outputs of TF(key,(0,i))
__device__ __forceinline__ unsigned int rb32(unsigned int k0, unsigned int k1,
                                             unsigned int i) {
  unsigned int y0, y1;
  threefry2x32(k0, k1, 0u, i, y0, y1);
  return y0 ^ y1;
}

__device__ __forceinline__ unsigned long long umin64(unsigned long long a,
                                                     unsigned long long b) {
  return a < b ? a : b;
}

// ---------------------------------------------------------------- K0: setup
__global__ __launch_bounds__(256) void k0_setup(const float* __restrict__ in,
                                                WS* __restrict__ ws) {
  const int b = blockIdx.x, t = threadIdx.x;
  for (int i = t; i < NBIN; i += 256) ws->hist[b][i] = 0u;
  if (t < NCLUST) {
    ws->cnt1[b][t] = 0u;
    // deterministic fallback init (pixel t) so a silent selection failure is
    // distinguishable from a crash: real picks in k4 overwrite these.
    const float* p = in + ((size_t)b * NPIX + (size_t)t) * 3;
    ws->centroids[b][t][0] = p[0];
    ws->centroids[b][t][1] = p[1];
    ws->centroids[b][t][2] = p[2];
    ws->sums[b][t][0] = 0.f; ws->sums[b][t][1] = 0.f;
    ws->sums[b][t][2] = 0.f; ws->sums[b][t][3] = 0.f;
  }
  if (t == 0) {
    ws->cnt2[b] = 0u;
    unsigned int kb0, kb1, ka0, ka1, u0, u1;
    threefry2x32(0u, 42u, 0u, (unsigned int)b, kb0, kb1);  // batch key (split of key(42))
    threefry2x32(kb0, kb1, 0u, 0u, ka0, ka1);              // carried key after round-1 split
    threefry2x32(kb0, kb1, 0u, 1u, u0, u1);                // round-1 subkey
    ws->subkeys[b][0] = u0; ws->subkeys[b][1] = u1;
    threefry2x32(ka0, ka1, 0u, 1u, u0, u1);                // round-2 subkey
    ws->subkeys[b][2] = u0; ws->subkeys[b][3] = u1;
  }
}

// ---------------------------------------------- K1: histogram r1 + capture r2
__global__ __launch_bounds__(256) void k1_scan(WS* __restrict__ ws) {
  const int b = blockIdx.x >> 5, chunk = blockIdx.x & 31, t = threadIdx.x;
  __shared__ unsigned int lhist[NBIN];
  for (int i = t; i < NBIN; i += 256) lhist[i] = 0u;
  __syncthreads();
  const unsigned int s1k0 = ws->subkeys[b][0], s1k1 = ws->subkeys[b][1];
  const unsigned int s2k0 = ws->subkeys[b][2], s2k1 = ws->subkeys[b][3];
  const unsigned int i0 = (unsigned int)chunk * 8192u;
  for (int j = 0; j < 32; ++j) {
    const unsigned int i = i0 + (unsigned int)(j * 256 + t);
    const unsigned int bits1 = rb32(s1k0, s1k1, i);
    atomicAdd(&lhist[bits1 >> 22], 1u);
    const unsigned int bits2 = rb32(s2k0, s2k1, i);
    if (bits2 < THRESH2) {
      const unsigned int pos = atomicAdd(&ws->cnt2[b], 1u);
      if (pos < CAP2)
        ws->list2[b][pos] = ((unsigned long long)bits2 << 18) | (unsigned long long)i;
    }
  }
  __syncthreads();
  for (int i = t; i < NBIN; i += 256)
    if (lhist[i]) atomicAdd(&ws->hist[b][i], lhist[i]);
}

// -------------------------- K2: top-8 of round-2; map ranks -> (bin, residual)
__global__ __launch_bounds__(256) void k2_select(WS* __restrict__ ws) {
  const int b = blockIdx.x, t = threadIdx.x;
  __shared__ unsigned long long lc[CAP2];
  __shared__ unsigned long long lr[256];
  __shared__ unsigned int lbins[NBIN + 1];
  __shared__ unsigned int lq[NCLUST];
  const unsigned int c2 = ws->cnt2[b];
  const int m2 = (int)(c2 < CAP2 ? c2 : CAP2);
  for (int e = t; e < m2; e += 256) lc[e] = ws->list2[b][e];
  __syncthreads();
  for (int j = 0; j < NCLUST; ++j) {
    unsigned long long lm = ~0ull;
    for (int e = t; e < m2; e += 256) lm = umin64(lm, lc[e]);
    lr[t] = lm;
    __syncthreads();
    for (int s = 128; s > 0; s >>= 1) {
      if (t < s) lr[t] = umin64(lr[t], lr[t + s]);
      __syncthreads();
    }
    const unsigned long long M = lr[0];
    if (t == 0) lq[j] = (unsigned int)(M & IDXMASK);   // q_j: rank into round-1 order
    for (int e = t; e < m2; e += 256)
      if (lc[e] == M) lc[e] = ~0ull;
    __syncthreads();
  }
  for (int i = t; i < NBIN; i += 256) lbins[i] = ws->hist[b][i];
  __syncthreads();
  if (t == 0) {  // exclusive prefix sum (serial; 1024 elems, negligible)
    unsigned int run = 0;
    for (int i = 0; i < NBIN; ++i) { const unsigned int c = lbins[i]; lbins[i] = run; run += c; }
    lbins[NBIN] = run;  // == NPIX
  }
  __syncthreads();
  for (int i = t; i < NBIN; i += 256) {
    const unsigned int lo = lbins[i], hi = lbins[i + 1];
    for (int j = 0; j < NCLUST; ++j) {
      const unsigned int q = lq[j];
      if (q >= lo && q < hi) { ws->binr[b][j][0] = (unsigned int)i; ws->binr[b][j][1] = q - lo; }
    }
  }
}

// --------------------------------------- K3: capture round-1 bin candidates
__global__ __launch_bounds__(256) void k3_scan(WS* __restrict__ ws) {
  const int b = blockIdx.x >> 5, chunk = blockIdx.x & 31, t = threadIdx.x;
  const unsigned int s1k0 = ws->subkeys[b][0], s1k1 = ws->subkeys[b][1];
  unsigned int bins[NCLUST];
#pragma unroll
  for (int j = 0; j < NCLUST; ++j) bins[j] = ws->binr[b][j][0];
  const unsigned int i0 = (unsigned int)chunk * 8192u;
  for (int jj = 0; jj < 32; ++jj) {
    const unsigned int i = i0 + (unsigned int)(jj * 256 + t);
    const unsigned int bits1 = rb32(s1k0, s1k1, i);
    const unsigned int bin = bits1 >> 22;
    const unsigned long long comp = ((unsigned long long)bits1 << 18) | (unsigned long long)i;
#pragma unroll
    for (int j = 0; j < NCLUST; ++j) {
      if (bin == bins[j]) {
        const unsigned int pos = atomicAdd(&ws->cnt1[b][j], 1u);
        if (pos < CAP1) ws->list1[b][j][pos] = comp;
      }
    }
  }
}

// ------------------- K4: in-bin rank selection -> init centroid gather
__global__ __launch_bounds__(256) void k4_pick(const float* __restrict__ in,
                                               WS* __restrict__ ws) {
  const int b = blockIdx.x >> 3, j = blockIdx.x & 7, t = threadIdx.x;
  __shared__ unsigned long long l1[CAP1];
  const unsigned int c1 = ws->cnt1[b][j];
  const int m = (int)(c1 < CAP1 ? c1 : CAP1);
  const unsigned int r = ws->binr[b][j][1];
  for (int e = t; e < m; e += 256) l1[e] = ws->list1[b][j][e];
  __syncthreads();
  for (int e = t; e < m; e += 256) {
    const unsigned long long v = l1[e];
    unsigned int rank = 0;
    for (int f = 0; f < m; ++f) rank += (l1[f] < v) ? 1u : 0u;
    if (rank == r) {
      const unsigned int i = (unsigned int)(v & IDXMASK);
      const float* p = in + ((size_t)b * NPIX + i) * 3;
      ws->centroids[b][j][0] = p[0];
      ws->centroids[b][j][1] = p[1];
      ws->centroids[b][j][2] = p[2];
    }
  }
}

// ------------------------------------ assign + accumulate (one per iteration)
__global__ __launch_bounds__(256) void kmeans_assign(const float* __restrict__ in,
                                                     WS* __restrict__ ws) {
  const int b = blockIdx.x >> 4, chunk = blockIdx.x & 15, t = threadIdx.x;
  float ca[NCLUST], cb[NCLUST], cc[NCLUST], cd[NCLUST];
#pragma unroll
  for (int k = 0; k < NCLUST; ++k) {
    const float x = ws->centroids[b][k][0];
    const float y = ws->centroids[b][k][1];
    const float z = ws->centroids[b][k][2];
    ca[k] = -2.f * x; cb[k] = -2.f * y; cc[k] = -2.f * z;
    cd[k] = fmaf(x, x, fmaf(y, y, z * z));     // argmin(-2 c.x + |c|^2) == argmin dist
  }
  float ax[NCLUST], ay[NCLUST], az[NCLUST], an[NCLUST];
#pragma unroll
  for (int k = 0; k < NCLUST; ++k) { ax[k] = 0.f; ay[k] = 0.f; az[k] = 0.f; an[k] = 0.f; }

  const float4* in4 = (const float4*)(in + (size_t)b * NPIX * 3);
  const int f4base = chunk * 12288;  // 16384 pixels * 3 floats / 4 per block
  for (int jj = 0; jj < 16; ++jj) {
    const int g = jj * 256 + t;               // 4-pixel group
    const int fb = f4base + g * 3;
    const float4 v0 = in4[fb], v1 = in4[fb + 1], v2 = in4[fb + 2];
    float px[4], py[4], pz[4];
    px[0] = v0.x; py[0] = v0.y; pz[0] = v0.z;
    px[1] = v0.w; py[1] = v1.x; pz[1] = v1.y;
    px[2] = v1.z; py[2] = v1.w; pz[2] = v2.x;
    px[3] = v2.y; py[3] = v2.z; pz[3] = v2.w;
#pragma unroll
    for (int p = 0; p < 4; ++p) {
      const float x = px[p], y = py[p], z = pz[p];
      float bv = fmaf(ca[0], x, fmaf(cb[0], y, fmaf(cc[0], z, cd[0])));
      int bk = 0;
#pragma unroll
      for (int k = 1; k < NCLUST; ++k) {
        const float tk = fmaf(ca[k], x, fmaf(cb[k], y, fmaf(cc[k], z, cd[k])));
        if (tk < bv) { bv = tk; bk = k; }     // strict <  => first-min, matches argmin
      }
#pragma unroll
      for (int k = 0; k < NCLUST; ++k) {
        const float w = (bk == k) ? 1.f : 0.f;
        ax[k] = fmaf(w, x, ax[k]);
        ay[k] = fmaf(w, y, ay[k]);
        az[k] = fmaf(w, z, az[k]);
        an[k] += w;
      }
    }
  }
  const int lane = t & 63;
#pragma unroll
  for (int k = 0; k < NCLUST; ++k) {
    float vx = ax[k], vy = ay[k], vz = az[k], vn = an[k];
#pragma unroll
    for (int off = 32; off > 0; off >>= 1) {
      vx += __shfl_down(vx, off, 64);
      vy += __shfl_down(vy, off, 64);
      vz += __shfl_down(vz, off, 64);
      vn += __shfl_down(vn, off, 64);
    }
    if (lane == 0) {
      atomicAdd(&ws->sums[b][k][0], vx);
      atomicAdd(&ws->sums[b][k][1], vy);
      atomicAdd(&ws->sums[b][k][2], vz);
      atomicAdd(&ws->sums[b][k][3], vn);
    }
  }
}

// ---------------------------------- centroid update (+ f32 output each iter)
__global__ __launch_bounds__(512) void kmeans_update(WS* __restrict__ ws,
                                                     float* __restrict__ out) {
  const int t = threadIdx.x;   // 512 = 64*8
  const int b = t >> 3, k = t & 7;
  const float sx = ws->sums[b][k][0];
  const float sy = ws->sums[b][k][1];
  const float sz = ws->sums[b][k][2];
  const float cnt = ws->sums[b][k][3];
  const float denom = fmaxf(cnt, 1.f);
  const float ox = ws->centroids[b][k][0];
  const float oy = ws->centroids[b][k][1];
  const float oz = ws->centroids[b][k][2];
  const float nx = (cnt > 0.f) ? sx / denom : ox;
  const float ny = (cnt > 0.f) ? sy / denom : oy;
  const float nz = (cnt > 0.f) ? sz / denom : oz;
  ws->centroids[b][k][0] = nx;
  ws->centroids[b][k][1] = ny;
  ws->centroids[b][k][2] = nz;
  const int o = (b * NCLUST + k) * 3;
  out[o + 0] = nx;
  out[o + 1] = ny;
  out[o + 2] = nz;
  ws->sums[b][k][0] = 0.f; ws->sums[b][k][1] = 0.f;
  ws->sums[b][k][2] = 0.f; ws->sums[b][k][3] = 0.f;
}

extern "C" void kernel_launch(void* const* d_in, const int* in_sizes, int n_in,
                              void* d_out, int out_size, void* d_ws, size_t ws_size,
                              hipStream_t stream) {
  const float* in = (const float*)d_in[0];
  float* out = (float*)d_out;
  WS* ws = (WS*)d_ws;   // ~2.6 MB of scratch

  k0_setup<<<NBATCH, 256, 0, stream>>>(in, ws);
  k1_scan<<<NBATCH * 32, 256, 0, stream>>>(ws);
  k2_select<<<NBATCH, 256, 0, stream>>>(ws);
  k3_scan<<<NBATCH * 32, 256, 0, stream>>>(ws);
  k4_pick<<<NBATCH * NCLUST, 256, 0, stream>>>(in, ws);
  for (int it = 0; it < NITER; ++it) {
    kmeans_assign<<<NBATCH * 16, 256, 0, stream>>>(in, ws);
    kmeans_update<<<1, 512, 0, stream>>>(ws, out);
  }
}